// Round 1
// baseline (1632.306 us; speedup 1.0000x reference)
//
#include <hip/hip_runtime.h>
#include <hip/hip_bf16.h>

// Problem constants (B=2, H=W=112, C=256, NHEAD=8, STRIP=7)
//   rows M = B*H*W = 25088, C = 256, 3C = 768
//   windows = 32, tokens/window L = 784, heads = 8, hd = 32
#define M_ROWS 25088
#define CDIM   256
#define QKVD   768
#define LWIN   784
#define NWINH  256   // 32 windows * 8 heads

static __device__ __forceinline__ float bf2f_lo(unsigned int u) {
    return __uint_as_float(u << 16);
}
static __device__ __forceinline__ float bf2f_hi(unsigned int u) {
    return __uint_as_float(u & 0xffff0000u);
}
static __device__ __forceinline__ float bfs2f(unsigned short s) {
    return __uint_as_float(((unsigned int)s) << 16);
}
static __device__ __forceinline__ unsigned short f2bf(float f) {
    unsigned int x = __float_as_uint(f);
    x += 0x7fffu + ((x >> 16) & 1u);
    return (unsigned short)(x >> 16);
}

// ---------------------------------------------------------------------------
// Kernel 1: qkv = x @ qkv_w^T   (fp32 in, bf16 out)
// A: (25088, 256) fp32 row-major, W: (768, 256) fp32 row-major (K contiguous)
// Y: (25088, 768) bf16
// Tile 64x64, K-chunks of 64. 256 threads, 4x4 register tile each.
// ---------------------------------------------------------------------------
__global__ __launch_bounds__(256) void k_qkv_gemm(
    const float* __restrict__ A, const float* __restrict__ W,
    unsigned short* __restrict__ Y)
{
    __shared__ float As[64][68];
    __shared__ float Ws[64][68];
    const int t  = threadIdx.x;
    const int C0 = blockIdx.x * 64;   // col tile (over 768)
    const int R0 = blockIdx.y * 64;   // row tile (over 25088)
    const int li = t >> 4;
    const int lk = (t & 15) << 2;
    const int tr = t >> 4;
    const int tc = t & 15;
    float acc[4][4] = {};

    for (int kc = 0; kc < CDIM; kc += 64) {
#pragma unroll
        for (int s = 0; s < 64; s += 16) {
            *(float4*)&As[li + s][lk] =
                *(const float4*)(A + (size_t)(R0 + li + s) * CDIM + kc + lk);
            *(float4*)&Ws[li + s][lk] =
                *(const float4*)(W + (size_t)(C0 + li + s) * CDIM + kc + lk);
        }
        __syncthreads();
#pragma unroll
        for (int k4 = 0; k4 < 16; ++k4) {
            float4 av[4], bv[4];
#pragma unroll
            for (int i = 0; i < 4; ++i) {
                av[i] = *(const float4*)&As[tr * 4 + i][k4 * 4];
                bv[i] = *(const float4*)&Ws[tc * 4 + i][k4 * 4];
            }
#pragma unroll
            for (int i = 0; i < 4; ++i)
#pragma unroll
                for (int j = 0; j < 4; ++j)
                    acc[i][j] += av[i].x * bv[j].x + av[i].y * bv[j].y +
                                 av[i].z * bv[j].z + av[i].w * bv[j].w;
        }
        __syncthreads();
    }
#pragma unroll
    for (int i = 0; i < 4; ++i) {
        ushort4 o;
        o.x = f2bf(acc[i][0]); o.y = f2bf(acc[i][1]);
        o.z = f2bf(acc[i][2]); o.w = f2bf(acc[i][3]);
        *(ushort4*)(Y + (size_t)(R0 + tr * 4 + i) * QKVD + C0 + tc * 4) = o;
    }
}

// ---------------------------------------------------------------------------
// Kernel 2: per-(window,head) softmax attention, fp32 math on bf16 q/k/v.
// One block (256 threads) per (window, head). K and V staged in LDS
// (rows padded to 17 dwords to kill the 32-way bank conflict at stride 16).
// Processes 4 query rows per iteration.
// ---------------------------------------------------------------------------
__global__ __launch_bounds__(256) void k_attn(
    const unsigned short* __restrict__ qkv,   // (25088, 768) bf16
    unsigned short* __restrict__ ao)          // (25088, 256) bf16
{
    extern __shared__ char smem[];
    unsigned int* Ku  = (unsigned int*)smem;            // 784*17 dwords = 53312 B
    unsigned int* Vu  = Ku + LWIN * 17;                 // 53312 B
    float*        qs  = (float*)(Vu + LWIN * 17);       // 4*32 floats
    float*        ps  = qs + 128;                        // 4*784 floats
    float*        wred = ps + 4 * LWIN;                  // 32 floats
    float*        opart = wred + 32;                     // 4*16*32 floats
    // total = 128000 bytes

    const int t = threadIdx.x;
    const int h = blockIdx.x & 7;
    const int w = blockIdx.x >> 3;
    const size_t rowbase = (size_t)w * LWIN;
    const unsigned int* qkvu = (const unsigned int*)qkv;  // row stride 384 dwords
    const int kof = 128 + h * 16;   // K block dword offset within row
    const int vof = 256 + h * 16;   // V block dword offset within row
    const float scale = 0.17677669529663687f;  // 32^-0.5

    // stage K, V into LDS (bf16 pairs as dwords), padded rows
    for (int idx = t; idx < LWIN * 16; idx += 256) {
        int m = idx >> 4, p = idx & 15;
        size_t rb = (rowbase + m) * 384;
        Ku[m * 17 + p] = qkvu[rb + kof + p];
        Vu[m * 17 + p] = qkvu[rb + vof + p];
    }

    const int wv = t >> 6;
    const int d2 = t & 15, g = t >> 4;
    const float2* q2 = (const float2*)qs;

    for (int rb4 = 0; rb4 < LWIN; rb4 += 4) {
        __syncthreads();   // protect qs/ps/opart (and first iter: K/V staged)
        if (t < 128) {
            int r = t >> 5, c = t & 31;
            qs[r * 32 + c] =
                scale * bfs2f(qkv[(rowbase + rb4 + r) * QKVD + h * 32 + c]);
        }
        __syncthreads();

        // logits for 4 rows; each thread owns m = t, t+256, t+512, (t+768)
        float lm0 = -3e38f, lm1 = -3e38f, lm2 = -3e38f, lm3 = -3e38f;
        for (int m = t; m < LWIN; m += 256) {
            const unsigned int* kr = Ku + m * 17;
            float l0 = 0.f, l1 = 0.f, l2 = 0.f, l3 = 0.f;
#pragma unroll
            for (int kd = 0; kd < 16; ++kd) {
                unsigned int u = kr[kd];
                float k0 = bf2f_lo(u), k1 = bf2f_hi(u);
                float2 qa = q2[kd];
                float2 qb = q2[16 + kd];
                float2 qc = q2[32 + kd];
                float2 qd = q2[48 + kd];
                l0 += qa.x * k0 + qa.y * k1;
                l1 += qb.x * k0 + qb.y * k1;
                l2 += qc.x * k0 + qc.y * k1;
                l3 += qd.x * k0 + qd.y * k1;
            }
            ps[m] = l0; ps[LWIN + m] = l1;
            ps[2 * LWIN + m] = l2; ps[3 * LWIN + m] = l3;
            lm0 = fmaxf(lm0, l0); lm1 = fmaxf(lm1, l1);
            lm2 = fmaxf(lm2, l2); lm3 = fmaxf(lm3, l3);
        }
#pragma unroll
        for (int off = 32; off > 0; off >>= 1) {
            lm0 = fmaxf(lm0, __shfl_xor(lm0, off));
            lm1 = fmaxf(lm1, __shfl_xor(lm1, off));
            lm2 = fmaxf(lm2, __shfl_xor(lm2, off));
            lm3 = fmaxf(lm3, __shfl_xor(lm3, off));
        }
        if ((t & 63) == 0) {
            wred[wv] = lm0; wred[4 + wv] = lm1;
            wred[8 + wv] = lm2; wred[12 + wv] = lm3;
        }
        __syncthreads();
        float gm0 = fmaxf(fmaxf(wred[0], wred[1]), fmaxf(wred[2], wred[3]));
        float gm1 = fmaxf(fmaxf(wred[4], wred[5]), fmaxf(wred[6], wred[7]));
        float gm2 = fmaxf(fmaxf(wred[8], wred[9]), fmaxf(wred[10], wred[11]));
        float gm3 = fmaxf(fmaxf(wred[12], wred[13]), fmaxf(wred[14], wred[15]));

        float ls0 = 0.f, ls1 = 0.f, ls2 = 0.f, ls3 = 0.f;
        for (int m = t; m < LWIN; m += 256) {
            float e0 = __expf(ps[m] - gm0);            ps[m] = e0;            ls0 += e0;
            float e1 = __expf(ps[LWIN + m] - gm1);     ps[LWIN + m] = e1;     ls1 += e1;
            float e2 = __expf(ps[2 * LWIN + m] - gm2); ps[2 * LWIN + m] = e2; ls2 += e2;
            float e3 = __expf(ps[3 * LWIN + m] - gm3); ps[3 * LWIN + m] = e3; ls3 += e3;
        }
#pragma unroll
        for (int off = 32; off > 0; off >>= 1) {
            ls0 += __shfl_xor(ls0, off);
            ls1 += __shfl_xor(ls1, off);
            ls2 += __shfl_xor(ls2, off);
            ls3 += __shfl_xor(ls3, off);
        }
        if ((t & 63) == 0) {
            wred[16 + wv] = ls0; wred[20 + wv] = ls1;
            wred[24 + wv] = ls2; wred[28 + wv] = ls3;
        }
        __syncthreads();
        float inv0 = 1.f / (wred[16] + wred[17] + wred[18] + wred[19]);
        float inv1 = 1.f / (wred[20] + wred[21] + wred[22] + wred[23]);
        float inv2 = 1.f / (wred[24] + wred[25] + wred[26] + wred[27]);
        float inv3 = 1.f / (wred[28] + wred[29] + wred[30] + wred[31]);

        // PV: thread (g, d2) handles m-stripe [g*49, g*49+49), d = 2*d2, 2*d2+1
        float a00 = 0.f, a01 = 0.f, a10 = 0.f, a11 = 0.f;
        float a20 = 0.f, a21 = 0.f, a30 = 0.f, a31 = 0.f;
        const int mbase = g * 49;
        for (int mi = 0; mi < 49; ++mi) {
            int m = mbase + mi;
            unsigned int vu = Vu[m * 17 + d2];
            float v0 = bf2f_lo(vu), v1 = bf2f_hi(vu);
            float p0 = ps[m], p1 = ps[LWIN + m];
            float p2 = ps[2 * LWIN + m], p3 = ps[3 * LWIN + m];
            a00 += p0 * v0; a01 += p0 * v1;
            a10 += p1 * v0; a11 += p1 * v1;
            a20 += p2 * v0; a21 += p2 * v1;
            a30 += p3 * v0; a31 += p3 * v1;
        }
        float* op = opart + g * 32 + d2 * 2;
        op[0]    = a00; op[1]    = a01;
        op[512]  = a10; op[513]  = a11;
        op[1024] = a20; op[1025] = a21;
        op[1536] = a30; op[1537] = a31;
        __syncthreads();
        if (t < 128) {
            int r = t >> 5, d = t & 31;
            const float* ob = opart + r * 512 + d;
            float s = 0.f;
#pragma unroll
            for (int g2 = 0; g2 < 16; ++g2) s += ob[g2 * 32];
            float invr = (r == 0) ? inv0 : (r == 1) ? inv1 : (r == 2) ? inv2 : inv3;
            ao[(rowbase + rb4 + r) * CDIM + h * 32 + d] = f2bf(s * invr);
        }
    }
}

// ---------------------------------------------------------------------------
// Kernel 3: out = ao @ proj_w^T + proj_b   (bf16 A, fp32 W/bias, fp32 out)
// ---------------------------------------------------------------------------
__global__ __launch_bounds__(256) void k_proj_gemm(
    const unsigned short* __restrict__ A,  // (25088, 256) bf16
    const float* __restrict__ W,           // (256, 256) fp32
    const float* __restrict__ bias,        // (256)
    float* __restrict__ Y)                 // (25088, 256) fp32
{
    __shared__ float As[64][68];
    __shared__ float Ws[64][68];
    const int t  = threadIdx.x;
    const int C0 = blockIdx.x * 64;
    const int R0 = blockIdx.y * 64;
    const int li = t >> 4;
    const int lk = (t & 15) << 2;
    const int tr = t >> 4;
    const int tc = t & 15;
    float acc[4][4] = {};

    for (int kc = 0; kc < CDIM; kc += 64) {
#pragma unroll
        for (int s = 0; s < 64; s += 16) {
            ushort4 a4 = *(const ushort4*)(A + (size_t)(R0 + li + s) * CDIM + kc + lk);
            float4 af;
            af.x = bfs2f(a4.x); af.y = bfs2f(a4.y);
            af.z = bfs2f(a4.z); af.w = bfs2f(a4.w);
            *(float4*)&As[li + s][lk] = af;
            *(float4*)&Ws[li + s][lk] =
                *(const float4*)(W + (size_t)(C0 + li + s) * CDIM + kc + lk);
        }
        __syncthreads();
#pragma unroll
        for (int k4 = 0; k4 < 16; ++k4) {
            float4 av[4], bv[4];
#pragma unroll
            for (int i = 0; i < 4; ++i) {
                av[i] = *(const float4*)&As[tr * 4 + i][k4 * 4];
                bv[i] = *(const float4*)&Ws[tc * 4 + i][k4 * 4];
            }
#pragma unroll
            for (int i = 0; i < 4; ++i)
#pragma unroll
                for (int j = 0; j < 4; ++j)
                    acc[i][j] += av[i].x * bv[j].x + av[i].y * bv[j].y +
                                 av[i].z * bv[j].z + av[i].w * bv[j].w;
        }
        __syncthreads();
    }
    float4 bb = *(const float4*)(bias + C0 + tc * 4);
#pragma unroll
    for (int i = 0; i < 4; ++i) {
        float4 o;
        o.x = acc[i][0] + bb.x; o.y = acc[i][1] + bb.y;
        o.z = acc[i][2] + bb.z; o.w = acc[i][3] + bb.w;
        *(float4*)(Y + (size_t)(R0 + tr * 4 + i) * CDIM + C0 + tc * 4) = o;
    }
}

extern "C" void kernel_launch(void* const* d_in, const int* in_sizes, int n_in,
                              void* d_out, int out_size, void* d_ws, size_t ws_size,
                              hipStream_t stream) {
    const float* x      = (const float*)d_in[0];
    const float* qkv_w  = (const float*)d_in[1];
    const float* proj_w = (const float*)d_in[2];
    const float* proj_b = (const float*)d_in[3];
    float* out = (float*)d_out;

    unsigned short* qkvb = (unsigned short*)d_ws;                 // 25088*768 bf16
    unsigned short* aob  = qkvb + (size_t)M_ROWS * QKVD;          // 25088*256 bf16

    // allow >64KB dynamic LDS for the attention kernel (idempotent, capture-safe)
    hipFuncSetAttribute((const void*)k_attn,
                        hipFuncAttributeMaxDynamicSharedMemorySize, 128000);

    k_qkv_gemm<<<dim3(QKVD / 64, M_ROWS / 64), 256, 0, stream>>>(x, qkv_w, qkvb);
    k_attn<<<dim3(NWINH), 256, 128000, stream>>>(qkvb, aob);
    k_proj_gemm<<<dim3(CDIM / 64, M_ROWS / 64), 256, 0, stream>>>(aob, proj_w, proj_b, out);
}

// Round 2
// 597.713 us; speedup vs baseline: 2.7309x; 2.7309x over previous
//
#include <hip/hip_runtime.h>
#include <hip/hip_bf16.h>

// Problem constants (B=2, H=W=112, C=256, NHEAD=8, STRIP=7)
#define M_ROWS 25088
#define CDIM   256
#define QKVD   768
#define LWIN   784
#define NWINH  256   // 32 windows * 8 heads

typedef __attribute__((ext_vector_type(8))) short short8v;
typedef __attribute__((ext_vector_type(4))) float floatx4;

static __device__ __forceinline__ float bfs2f(unsigned short s) {
    return __uint_as_float(((unsigned int)s) << 16);
}
static __device__ __forceinline__ unsigned short f2bf(float f) {
    unsigned int x = __float_as_uint(f);
    x += 0x7fffu + ((x >> 16) & 1u);
    return (unsigned short)(x >> 16);
}
static __device__ __forceinline__ unsigned int cvt_pk_bf16(float a, float b) {
    unsigned int r;
    asm("v_cvt_pk_bf16_f32 %0, %1, %2" : "=v"(r) : "v"(a), "v"(b));
    return r;  // lo16 = bf16(a), hi16 = bf16(b)
}

// ---------------------------------------------------------------------------
// Kernel 1: qkv = x @ qkv_w^T   (fp32 in, bf16 out)  [unchanged from R1]
// ---------------------------------------------------------------------------
__global__ __launch_bounds__(256) void k_qkv_gemm(
    const float* __restrict__ A, const float* __restrict__ W,
    unsigned short* __restrict__ Y)
{
    __shared__ float As[64][68];
    __shared__ float Ws[64][68];
    const int t  = threadIdx.x;
    const int C0 = blockIdx.x * 64;
    const int R0 = blockIdx.y * 64;
    const int li = t >> 4;
    const int lk = (t & 15) << 2;
    const int tr = t >> 4;
    const int tc = t & 15;
    float acc[4][4] = {};

    for (int kc = 0; kc < CDIM; kc += 64) {
#pragma unroll
        for (int s = 0; s < 64; s += 16) {
            *(float4*)&As[li + s][lk] =
                *(const float4*)(A + (size_t)(R0 + li + s) * CDIM + kc + lk);
            *(float4*)&Ws[li + s][lk] =
                *(const float4*)(W + (size_t)(C0 + li + s) * CDIM + kc + lk);
        }
        __syncthreads();
#pragma unroll
        for (int k4 = 0; k4 < 16; ++k4) {
            float4 av[4], bv[4];
#pragma unroll
            for (int i = 0; i < 4; ++i) {
                av[i] = *(const float4*)&As[tr * 4 + i][k4 * 4];
                bv[i] = *(const float4*)&Ws[tc * 4 + i][k4 * 4];
            }
#pragma unroll
            for (int i = 0; i < 4; ++i)
#pragma unroll
                for (int j = 0; j < 4; ++j)
                    acc[i][j] += av[i].x * bv[j].x + av[i].y * bv[j].y +
                                 av[i].z * bv[j].z + av[i].w * bv[j].w;
        }
        __syncthreads();
    }
#pragma unroll
    for (int i = 0; i < 4; ++i) {
        ushort4 o;
        o.x = f2bf(acc[i][0]); o.y = f2bf(acc[i][1]);
        o.z = f2bf(acc[i][2]); o.w = f2bf(acc[i][3]);
        *(ushort4*)(Y + (size_t)(R0 + tr * 4 + i) * QKVD + C0 + tc * 4) = o;
    }
}

// ---------------------------------------------------------------------------
// Kernel 2: MFMA attention, swapped-QK^T, no-max online softmax.
// One block (8 waves) per (window, head). K in LDS as [4][784][8] (kgroup-
// major, 16B frags), V transposed to Vt[32][808], P wave-private roundtrip.
// ---------------------------------------------------------------------------
#define VTP 808                       // Vt row pitch (shorts)
#define KS_SZ (LWIN * 32)             // 25088 shorts
#define VT_SZ (32 * VTP)              // 25856 shorts
#define PB_OFF (KS_SZ + VT_SZ)        // 50944 shorts
#define ATTN_LDS ((PB_OFF + 8 * 1280) * 2)   // 122368 bytes

__global__ __launch_bounds__(512, 1) void k_attn_mfma(
    const unsigned short* __restrict__ qkv,   // (25088, 768) bf16
    unsigned short* __restrict__ ao)          // (25088, 256) bf16
{
    extern __shared__ unsigned short sm[];
    unsigned short* Ks = sm;            // [4 kgroup][784 tok][8]
    unsigned short* Vt = sm + KS_SZ;    // [32 dim][808]
    const int t = threadIdx.x;
    const int lane = t & 63, wave = t >> 6;
    const int lq = lane & 15, g = lane >> 4;
    const int h = blockIdx.x & 7, w = blockIdx.x >> 3;
    const size_t rowbase = (size_t)w * LWIN;
    const unsigned short* base = qkv + rowbase * QKVD;

    // ---- stage K (kgroup-major) and V (transposed) ----
    for (int idx = t; idx < LWIN * 4; idx += 512) {
        const int row = idx >> 2, c = idx & 3;
        const size_t rb = (size_t)row * QKVD;
        uint4 kv = *(const uint4*)(base + rb + 256 + h * 32 + c * 8);
        *(uint4*)(Ks + c * (LWIN * 8) + row * 8) = kv;
        union { uint4 u; unsigned short s[8]; } vv;
        vv.u = *(const uint4*)(base + rb + 512 + h * 32 + c * 8);
#pragma unroll
        for (int j = 0; j < 8; ++j) Vt[(c * 8 + j) * VTP + row] = vv.s[j];
    }
    // zero Vt pad cols 784..807 (read by the odd-tail PV with P==0)
    for (int idx = t; idx < 32 * 24; idx += 512) {
        Vt[(idx / 24) * VTP + LWIN + (idx % 24)] = 0;
    }
    __syncthreads();

    unsigned short* Pw = sm + PB_OFF + wave * 1280;  // 2 tiles x [16][40]
    const float CE = 1.4426950408889634f * 0.17677669529663687f; // log2e*scale

    for (int c = wave; c < 25; c += 8) {
        const int tile0 = c * 2;
        const int nt = (c == 24) ? 1 : 2;
        short8v qf[2];
#pragma unroll
        for (int n = 0; n < 2; ++n)
            if (n < nt)
                qf[n] = *(const short8v*)(base +
                        (size_t)((tile0 + n) * 16 + lq) * QKVD + h * 32 + g * 8);

        floatx4 oa[2][2] = {{{0.f,0.f,0.f,0.f},{0.f,0.f,0.f,0.f}},
                            {{0.f,0.f,0.f,0.f},{0.f,0.f,0.f,0.f}}};
        float lsum[2] = {0.f, 0.f};

        auto do_score = [&](int s) {
            short8v kf = *(const short8v*)(Ks + g * (LWIN * 8) +
                                           (size_t)(s * 16 + lq) * 8);
#pragma unroll
            for (int n = 0; n < 2; ++n) {
                if (n < nt) {
                    floatx4 st = __builtin_amdgcn_mfma_f32_16x16x32_bf16(
                        kf, qf[n], (floatx4){0.f, 0.f, 0.f, 0.f}, 0, 0, 0);
                    float p0 = __builtin_amdgcn_exp2f(st[0] * CE);
                    float p1 = __builtin_amdgcn_exp2f(st[1] * CE);
                    float p2 = __builtin_amdgcn_exp2f(st[2] * CE);
                    float p3 = __builtin_amdgcn_exp2f(st[3] * CE);
                    lsum[n] += (p0 + p1) + (p2 + p3);
                    uint2 pw;
                    pw.x = cvt_pk_bf16(p0, p1);
                    pw.y = cvt_pk_bf16(p2, p3);
                    *(uint2*)(Pw + n * 640 + lq * 40 + (s & 1) * 16 + g * 4) = pw;
                }
            }
        };
        auto do_pv = [&](int tokbase) {
            short8v v0 = *(const short8v*)(Vt + (size_t)lq * VTP + tokbase + g * 8);
            short8v v1 = *(const short8v*)(Vt + (size_t)(lq + 16) * VTP + tokbase + g * 8);
#pragma unroll
            for (int n = 0; n < 2; ++n) {
                if (n < nt) {
                    short8v pf = *(const short8v*)(Pw + n * 640 + lq * 40 + g * 8);
                    oa[n][0] = __builtin_amdgcn_mfma_f32_16x16x32_bf16(
                        pf, v0, oa[n][0], 0, 0, 0);
                    oa[n][1] = __builtin_amdgcn_mfma_f32_16x16x32_bf16(
                        pf, v1, oa[n][1], 0, 0, 0);
                }
            }
        };

        for (int u = 0; u < 24; ++u) {
            do_score(2 * u);
            do_score(2 * u + 1);
            do_pv(u * 32);
        }
        do_score(48);
#pragma unroll
        for (int n = 0; n < 2; ++n) {   // zero P cols 16..31 for the tail PV
            if (n < nt) {
                uint2 z; z.x = 0u; z.y = 0u;
                *(uint2*)(Pw + n * 640 + lq * 40 + 16 + g * 4) = z;
            }
        }
        do_pv(768);

        // ---- normalize + store ----
#pragma unroll
        for (int n = 0; n < 2; ++n) {
            if (n < nt) {
                float l = lsum[n];
                l += __shfl_xor(l, 16);
                l += __shfl_xor(l, 32);
                float inv = 1.f / l;
                const size_t orow0 = rowbase + (size_t)(tile0 + n) * 16;
#pragma unroll
                for (int r = 0; r < 4; ++r) {
                    float ir = __shfl(inv, (lane & 48) | (g * 4 + r));
                    size_t ob = (orow0 + g * 4 + r) * CDIM + h * 32;
                    ao[ob + lq]      = f2bf(oa[n][0][r] * ir);
                    ao[ob + 16 + lq] = f2bf(oa[n][1][r] * ir);
                }
            }
        }
    }
}

// ---------------------------------------------------------------------------
// Kernel 3: out = ao @ proj_w^T + proj_b   [unchanged from R1]
// ---------------------------------------------------------------------------
__global__ __launch_bounds__(256) void k_proj_gemm(
    const unsigned short* __restrict__ A,
    const float* __restrict__ W,
    const float* __restrict__ bias,
    float* __restrict__ Y)
{
    __shared__ float As[64][68];
    __shared__ float Ws[64][68];
    const int t  = threadIdx.x;
    const int C0 = blockIdx.x * 64;
    const int R0 = blockIdx.y * 64;
    const int li = t >> 4;
    const int lk = (t & 15) << 2;
    const int tr = t >> 4;
    const int tc = t & 15;
    float acc[4][4] = {};

    for (int kc = 0; kc < CDIM; kc += 64) {
#pragma unroll
        for (int s = 0; s < 64; s += 16) {
            ushort4 a4 = *(const ushort4*)(A + (size_t)(R0 + li + s) * CDIM + kc + lk);
            float4 af;
            af.x = bfs2f(a4.x); af.y = bfs2f(a4.y);
            af.z = bfs2f(a4.z); af.w = bfs2f(a4.w);
            *(float4*)&As[li + s][lk] = af;
            *(float4*)&Ws[li + s][lk] =
                *(const float4*)(W + (size_t)(C0 + li + s) * CDIM + kc + lk);
        }
        __syncthreads();
#pragma unroll
        for (int k4 = 0; k4 < 16; ++k4) {
            float4 av[4], bv[4];
#pragma unroll
            for (int i = 0; i < 4; ++i) {
                av[i] = *(const float4*)&As[tr * 4 + i][k4 * 4];
                bv[i] = *(const float4*)&Ws[tc * 4 + i][k4 * 4];
            }
#pragma unroll
            for (int i = 0; i < 4; ++i)
#pragma unroll
                for (int j = 0; j < 4; ++j)
                    acc[i][j] += av[i].x * bv[j].x + av[i].y * bv[j].y +
                                 av[i].z * bv[j].z + av[i].w * bv[j].w;
        }
        __syncthreads();
    }
    float4 bb = *(const float4*)(bias + C0 + tc * 4);
#pragma unroll
    for (int i = 0; i < 4; ++i) {
        float4 o;
        o.x = acc[i][0] + bb.x; o.y = acc[i][1] + bb.y;
        o.z = acc[i][2] + bb.z; o.w = acc[i][3] + bb.w;
        *(float4*)(Y + (size_t)(R0 + tr * 4 + i) * CDIM + C0 + tc * 4) = o;
    }
}

extern "C" void kernel_launch(void* const* d_in, const int* in_sizes, int n_in,
                              void* d_out, int out_size, void* d_ws, size_t ws_size,
                              hipStream_t stream) {
    const float* x      = (const float*)d_in[0];
    const float* qkv_w  = (const float*)d_in[1];
    const float* proj_w = (const float*)d_in[2];
    const float* proj_b = (const float*)d_in[3];
    float* out = (float*)d_out;

    unsigned short* qkvb = (unsigned short*)d_ws;                 // 25088*768 bf16
    unsigned short* aob  = qkvb + (size_t)M_ROWS * QKVD;          // 25088*256 bf16

    hipFuncSetAttribute((const void*)k_attn_mfma,
                        hipFuncAttributeMaxDynamicSharedMemorySize, ATTN_LDS);

    k_qkv_gemm<<<dim3(QKVD / 64, M_ROWS / 64), 256, 0, stream>>>(x, qkv_w, qkvb);
    k_attn_mfma<<<dim3(NWINH), 512, ATTN_LDS, stream>>>(qkvb, aob);
    k_proj_gemm<<<dim3(CDIM / 64, M_ROWS / 64), 256, 0, stream>>>(aob, proj_w, proj_b, out);
}

// Round 3
// 98.704 us; speedup vs baseline: 16.5374x; 6.0556x over previous
//
#include <hip/hip_runtime.h>
#include <hip/hip_bf16.h>

// Problem constants (B=2, H=W=112, C=256, NHEAD=8, STRIP=7)
#define M_ROWS 25088
#define CDIM   256
#define QKVD   768
#define LWIN   784
#define NWINH  256   // 32 windows * 8 heads

typedef __attribute__((ext_vector_type(8))) short short8v;
typedef __attribute__((ext_vector_type(4))) float floatx4;

static __device__ __forceinline__ float bfs2f(unsigned short s) {
    return __uint_as_float(((unsigned int)s) << 16);
}
static __device__ __forceinline__ unsigned short f2bf(float f) {
    unsigned int x = __float_as_uint(f);
    x += 0x7fffu + ((x >> 16) & 1u);
    return (unsigned short)(x >> 16);
}
static __device__ __forceinline__ unsigned int cvt_pk_bf16(float a, float b) {
    unsigned int r;
    asm("v_cvt_pk_bf16_f32 %0, %1, %2" : "=v"(r) : "v"(a), "v"(b));
    return r;  // lo16 = bf16(a), hi16 = bf16(b)
}
static __device__ __forceinline__ void gld_lds16(const unsigned short* g,
                                                 unsigned short* l) {
    __builtin_amdgcn_global_load_lds(
        (const __attribute__((address_space(1))) unsigned int*)g,
        (__attribute__((address_space(3))) unsigned int*)l, 16, 0, 0);
}

// ---------------------------------------------------------------------------
// Kernel 0: fp32 -> bf16 pack (8 floats / thread / iter)
// ---------------------------------------------------------------------------
__global__ __launch_bounds__(256) void k_f2bf(
    const float* __restrict__ src, unsigned short* __restrict__ dst, int n8)
{
    const float4* s4 = (const float4*)src;
    uint4* d4 = (uint4*)dst;
    for (int i = blockIdx.x * 256 + threadIdx.x; i < n8;
         i += gridDim.x * 256) {
        float4 a = s4[2 * i], b = s4[2 * i + 1];
        uint4 o;
        o.x = cvt_pk_bf16(a.x, a.y);
        o.y = cvt_pk_bf16(a.z, a.w);
        o.z = cvt_pk_bf16(b.x, b.y);
        o.w = cvt_pk_bf16(b.z, b.w);
        d4[i] = o;
    }
}

// ---------------------------------------------------------------------------
// Kernel 1/3: C(M,N) = A(M,256) @ B(N,256)^T [+ bias], bf16 MFMA.
// 128x128 tile, BK=64, 256 threads = 4 waves (2x2), 64x64 per wave,
// 4x4 16x16x32 fragments. Staging: global_load_lds width 16, linear LDS.
// ---------------------------------------------------------------------------
template <typename OUT_T, bool BIAS>
__global__ __launch_bounds__(256, 2) void k_gemm_mfma(
    const unsigned short* __restrict__ A,   // (M, 256) bf16
    const unsigned short* __restrict__ B,   // (N, 256) bf16
    const float* __restrict__ bias,         // (N) or nullptr
    OUT_T* __restrict__ Y, int N)           // (M, N)
{
    __shared__ __attribute__((aligned(16))) unsigned short As[128 * 64];
    __shared__ __attribute__((aligned(16))) unsigned short Bs[128 * 64];
    const int t = threadIdx.x;
    const int lane = t & 63, wv = t >> 6;
    const int lq = lane & 15, g = lane >> 4;
    const int wm = wv >> 1, wn = wv & 1;
    const int R0 = blockIdx.y * 128, C0 = blockIdx.x * 128;
    const int lrow = t >> 3, lch = (t & 7) * 8;   // staging: 32 rows / issue

    floatx4 acc[4][4];
#pragma unroll
    for (int i = 0; i < 4; ++i)
#pragma unroll
        for (int j = 0; j < 4; ++j) acc[i][j] = (floatx4){0.f, 0.f, 0.f, 0.f};

    for (int kc = 0; kc < 256; kc += 64) {
#pragma unroll
        for (int i = 0; i < 4; ++i) {
            // wave-uniform LDS base + lane*16B == row (i*32+wv*8+(l>>3)), col (l&7)*8
            gld_lds16(A + (size_t)(R0 + i * 32 + lrow) * 256 + kc + lch,
                      As + (i * 32 + wv * 8) * 64);
            gld_lds16(B + (size_t)(C0 + i * 32 + lrow) * 256 + kc + lch,
                      Bs + (i * 32 + wv * 8) * 64);
        }
        __syncthreads();
#pragma unroll
        for (int kk = 0; kk < 64; kk += 32) {
            short8v af[4], bf[4];
#pragma unroll
            for (int mi = 0; mi < 4; ++mi)
                af[mi] = *(const short8v*)(As + (wm * 64 + mi * 16 + lq) * 64 +
                                           kk + g * 8);
#pragma unroll
            for (int ni = 0; ni < 4; ++ni)
                bf[ni] = *(const short8v*)(Bs + (wn * 64 + ni * 16 + lq) * 64 +
                                           kk + g * 8);
#pragma unroll
            for (int mi = 0; mi < 4; ++mi)
#pragma unroll
                for (int ni = 0; ni < 4; ++ni)
                    acc[mi][ni] = __builtin_amdgcn_mfma_f32_16x16x32_bf16(
                        af[mi], bf[ni], acc[mi][ni], 0, 0, 0);
        }
        __syncthreads();
    }

#pragma unroll
    for (int mi = 0; mi < 4; ++mi) {
        const size_t rb = (size_t)R0 + wm * 64 + mi * 16 + g * 4;
#pragma unroll
        for (int ni = 0; ni < 4; ++ni) {
            const int col = C0 + wn * 64 + ni * 16 + lq;
            float bv = 0.f;
            if constexpr (BIAS) bv = bias[col];
#pragma unroll
            for (int r = 0; r < 4; ++r) {
                float val = acc[mi][ni][r] + bv;
                if constexpr (sizeof(OUT_T) == 2)
                    Y[(rb + r) * N + col] = (OUT_T)f2bf(val);
                else
                    Y[(rb + r) * N + col] = (OUT_T)val;
            }
        }
    }
}

// ---------------------------------------------------------------------------
// Kernel 2: MFMA attention, swapped-QK^T, no-max softmax. [unchanged from R2]
// ---------------------------------------------------------------------------
#define VTP 808
#define KS_SZ (LWIN * 32)
#define VT_SZ (32 * VTP)
#define PB_OFF (KS_SZ + VT_SZ)
#define ATTN_LDS ((PB_OFF + 8 * 1280) * 2)   // 122368 bytes

__global__ __launch_bounds__(512, 1) void k_attn_mfma(
    const unsigned short* __restrict__ qkv,   // (25088, 768) bf16
    unsigned short* __restrict__ ao)          // (25088, 256) bf16
{
    extern __shared__ unsigned short sm[];
    unsigned short* Ks = sm;            // [4 kgroup][784 tok][8]
    unsigned short* Vt = sm + KS_SZ;    // [32 dim][808]
    const int t = threadIdx.x;
    const int lane = t & 63, wave = t >> 6;
    const int lq = lane & 15, g = lane >> 4;
    const int h = blockIdx.x & 7, w = blockIdx.x >> 3;
    const size_t rowbase = (size_t)w * LWIN;
    const unsigned short* base = qkv + rowbase * QKVD;

    for (int idx = t; idx < LWIN * 4; idx += 512) {
        const int row = idx >> 2, c = idx & 3;
        const size_t rb = (size_t)row * QKVD;
        uint4 kv = *(const uint4*)(base + rb + 256 + h * 32 + c * 8);
        *(uint4*)(Ks + c * (LWIN * 8) + row * 8) = kv;
        union { uint4 u; unsigned short s[8]; } vv;
        vv.u = *(const uint4*)(base + rb + 512 + h * 32 + c * 8);
#pragma unroll
        for (int j = 0; j < 8; ++j) Vt[(c * 8 + j) * VTP + row] = vv.s[j];
    }
    for (int idx = t; idx < 32 * 24; idx += 512) {
        Vt[(idx / 24) * VTP + LWIN + (idx % 24)] = 0;
    }
    __syncthreads();

    unsigned short* Pw = sm + PB_OFF + wave * 1280;  // 2 tiles x [16][40]
    const float CE = 1.4426950408889634f * 0.17677669529663687f;

    for (int c = wave; c < 25; c += 8) {
        const int tile0 = c * 2;
        const int nt = (c == 24) ? 1 : 2;
        short8v qf[2];
#pragma unroll
        for (int n = 0; n < 2; ++n)
            if (n < nt)
                qf[n] = *(const short8v*)(base +
                        (size_t)((tile0 + n) * 16 + lq) * QKVD + h * 32 + g * 8);

        floatx4 oa[2][2] = {{{0.f,0.f,0.f,0.f},{0.f,0.f,0.f,0.f}},
                            {{0.f,0.f,0.f,0.f},{0.f,0.f,0.f,0.f}}};
        float lsum[2] = {0.f, 0.f};

        auto do_score = [&](int s) {
            short8v kf = *(const short8v*)(Ks + g * (LWIN * 8) +
                                           (size_t)(s * 16 + lq) * 8);
#pragma unroll
            for (int n = 0; n < 2; ++n) {
                if (n < nt) {
                    floatx4 st = __builtin_amdgcn_mfma_f32_16x16x32_bf16(
                        kf, qf[n], (floatx4){0.f, 0.f, 0.f, 0.f}, 0, 0, 0);
                    float p0 = __builtin_amdgcn_exp2f(st[0] * CE);
                    float p1 = __builtin_amdgcn_exp2f(st[1] * CE);
                    float p2 = __builtin_amdgcn_exp2f(st[2] * CE);
                    float p3 = __builtin_amdgcn_exp2f(st[3] * CE);
                    lsum[n] += (p0 + p1) + (p2 + p3);
                    uint2 pw;
                    pw.x = cvt_pk_bf16(p0, p1);
                    pw.y = cvt_pk_bf16(p2, p3);
                    *(uint2*)(Pw + n * 640 + lq * 40 + (s & 1) * 16 + g * 4) = pw;
                }
            }
        };
        auto do_pv = [&](int tokbase) {
            short8v v0 = *(const short8v*)(Vt + (size_t)lq * VTP + tokbase + g * 8);
            short8v v1 = *(const short8v*)(Vt + (size_t)(lq + 16) * VTP + tokbase + g * 8);
#pragma unroll
            for (int n = 0; n < 2; ++n) {
                if (n < nt) {
                    short8v pf = *(const short8v*)(Pw + n * 640 + lq * 40 + g * 8);
                    oa[n][0] = __builtin_amdgcn_mfma_f32_16x16x32_bf16(
                        pf, v0, oa[n][0], 0, 0, 0);
                    oa[n][1] = __builtin_amdgcn_mfma_f32_16x16x32_bf16(
                        pf, v1, oa[n][1], 0, 0, 0);
                }
            }
        };

        for (int u = 0; u < 24; ++u) {
            do_score(2 * u);
            do_score(2 * u + 1);
            do_pv(u * 32);
        }
        do_score(48);
#pragma unroll
        for (int n = 0; n < 2; ++n) {
            if (n < nt) {
                uint2 z; z.x = 0u; z.y = 0u;
                *(uint2*)(Pw + n * 640 + lq * 40 + 16 + g * 4) = z;
            }
        }
        do_pv(768);

#pragma unroll
        for (int n = 0; n < 2; ++n) {
            if (n < nt) {
                float l = lsum[n];
                l += __shfl_xor(l, 16);
                l += __shfl_xor(l, 32);
                float inv = 1.f / l;
                const size_t orow0 = rowbase + (size_t)(tile0 + n) * 16;
#pragma unroll
                for (int r = 0; r < 4; ++r) {
                    float ir = __shfl(inv, (lane & 48) | (g * 4 + r));
                    size_t ob = (orow0 + g * 4 + r) * CDIM + h * 32;
                    ao[ob + lq]      = f2bf(oa[n][0][r] * ir);
                    ao[ob + 16 + lq] = f2bf(oa[n][1][r] * ir);
                }
            }
        }
    }
}

extern "C" void kernel_launch(void* const* d_in, const int* in_sizes, int n_in,
                              void* d_out, int out_size, void* d_ws, size_t ws_size,
                              hipStream_t stream) {
    const float* x      = (const float*)d_in[0];
    const float* qkv_w  = (const float*)d_in[1];
    const float* proj_w = (const float*)d_in[2];
    const float* proj_b = (const float*)d_in[3];
    float* out = (float*)d_out;

    // ws layout (bytes):
    //   [0, 38535168)           qkvb  (25088x768 bf16)
    //   [38535168, 51380224)    xb (during GEMM1) / aob (after attn) -- aliased
    //   [51380224, 51773440)    wqb   (768x256 bf16)
    //   [51773440, 51904512)    wpb   (256x256 bf16)
    unsigned short* qkvb = (unsigned short*)d_ws;
    unsigned short* xb   = qkvb + (size_t)M_ROWS * QKVD;
    unsigned short* aob  = xb;  // alias: xb dead once GEMM1 completes
    unsigned short* wqb  = xb + (size_t)M_ROWS * CDIM;
    unsigned short* wpb  = wqb + (size_t)QKVD * CDIM;

    hipFuncSetAttribute((const void*)k_attn_mfma,
                        hipFuncAttributeMaxDynamicSharedMemorySize, ATTN_LDS);

    k_f2bf<<<2048, 256, 0, stream>>>(x, xb, (M_ROWS * CDIM) / 8);
    k_f2bf<<<96, 256, 0, stream>>>(qkv_w, wqb, (QKVD * CDIM) / 8);
    k_f2bf<<<32, 256, 0, stream>>>(proj_w, wpb, (CDIM * CDIM) / 8);

    k_gemm_mfma<unsigned short, false>
        <<<dim3(QKVD / 128, M_ROWS / 128), 256, 0, stream>>>(
            xb, wqb, nullptr, qkvb, QKVD);

    k_attn_mfma<<<dim3(NWINH), 512, ATTN_LDS, stream>>>(qkvb, aob);

    k_gemm_mfma<float, true>
        <<<dim3(CDIM / 128, M_ROWS / 128), 256, 0, stream>>>(
            aob, wpb, proj_b, out, CDIM);
}

// Round 4
// 90.352 us; speedup vs baseline: 18.0660x; 1.0924x over previous
//
#include <hip/hip_runtime.h>
#include <hip/hip_bf16.h>

// Problem constants (B=2, H=W=112, C=256, NHEAD=8, STRIP=7)
#define M_ROWS 25088
#define CDIM   256
#define QKVD   768
#define LWIN   784
#define NWINH  256   // 32 windows * 8 heads

typedef __attribute__((ext_vector_type(8))) short short8v;
typedef __attribute__((ext_vector_type(4))) float floatx4;

// scale * log2(e) = (1/sqrt(32)) * 1.4426950408889634
#define CEQ 0.2550660106245232f

static __device__ __forceinline__ float bfs2f(unsigned short s) {
    return __uint_as_float(((unsigned int)s) << 16);
}
static __device__ __forceinline__ unsigned short f2bf(float f) {
    unsigned int x = __float_as_uint(f);
    x += 0x7fffu + ((x >> 16) & 1u);
    return (unsigned short)(x >> 16);
}
static __device__ __forceinline__ unsigned int cvt_pk_bf16(float a, float b) {
    unsigned int r;
    asm("v_cvt_pk_bf16_f32 %0, %1, %2" : "=v"(r) : "v"(a), "v"(b));
    return r;  // lo16 = bf16(a), hi16 = bf16(b)
}
static __device__ __forceinline__ void gld_lds16(const unsigned short* g,
                                                 unsigned short* l) {
    __builtin_amdgcn_global_load_lds(
        (const __attribute__((address_space(1))) unsigned int*)g,
        (__attribute__((address_space(3))) unsigned int*)l, 16, 0, 0);
}

// ---------------------------------------------------------------------------
// Kernel 0: fp32 -> bf16 pack (8 floats / thread / iter)
// ---------------------------------------------------------------------------
__global__ __launch_bounds__(256) void k_f2bf(
    const float* __restrict__ src, unsigned short* __restrict__ dst, int n8)
{
    const float4* s4 = (const float4*)src;
    uint4* d4 = (uint4*)dst;
    for (int i = blockIdx.x * 256 + threadIdx.x; i < n8;
         i += gridDim.x * 256) {
        float4 a = s4[2 * i], b = s4[2 * i + 1];
        uint4 o;
        o.x = cvt_pk_bf16(a.x, a.y);
        o.y = cvt_pk_bf16(a.z, a.w);
        o.z = cvt_pk_bf16(b.x, b.y);
        o.w = cvt_pk_bf16(b.z, b.w);
        d4[i] = o;
    }
}

// ---------------------------------------------------------------------------
// Kernel 1/3: C(M,N) = A(M,256) @ B(N,256)^T [+ bias], bf16 MFMA.
// 128x128 tile, BK=64, 256 threads = 4 waves (2x2), 64x64 per wave.
// SCALEQ: multiply cols 0..255 (the Q block of qkv) by CEQ in the epilogue,
// pre-folding softmax scale*log2e into Q at zero cost.
// ---------------------------------------------------------------------------
template <typename OUT_T, bool BIAS, bool SCALEQ>
__global__ __launch_bounds__(256, 2) void k_gemm_mfma(
    const unsigned short* __restrict__ A,   // (M, 256) bf16
    const unsigned short* __restrict__ B,   // (N, 256) bf16
    const float* __restrict__ bias,         // (N) or nullptr
    OUT_T* __restrict__ Y, int N)           // (M, N)
{
    __shared__ __attribute__((aligned(16))) unsigned short As[128 * 64];
    __shared__ __attribute__((aligned(16))) unsigned short Bs[128 * 64];
    const int t = threadIdx.x;
    const int lane = t & 63, wv = t >> 6;
    const int lq = lane & 15, g = lane >> 4;
    const int wm = wv >> 1, wn = wv & 1;
    const int R0 = blockIdx.y * 128, C0 = blockIdx.x * 128;
    const int lrow = t >> 3, lch = (t & 7) * 8;

    floatx4 acc[4][4];
#pragma unroll
    for (int i = 0; i < 4; ++i)
#pragma unroll
        for (int j = 0; j < 4; ++j) acc[i][j] = (floatx4){0.f, 0.f, 0.f, 0.f};

    for (int kc = 0; kc < 256; kc += 64) {
#pragma unroll
        for (int i = 0; i < 4; ++i) {
            gld_lds16(A + (size_t)(R0 + i * 32 + lrow) * 256 + kc + lch,
                      As + (i * 32 + wv * 8) * 64);
            gld_lds16(B + (size_t)(C0 + i * 32 + lrow) * 256 + kc + lch,
                      Bs + (i * 32 + wv * 8) * 64);
        }
        __syncthreads();
#pragma unroll
        for (int kk = 0; kk < 64; kk += 32) {
            short8v af[4], bf[4];
#pragma unroll
            for (int mi = 0; mi < 4; ++mi)
                af[mi] = *(const short8v*)(As + (wm * 64 + mi * 16 + lq) * 64 +
                                           kk + g * 8);
#pragma unroll
            for (int ni = 0; ni < 4; ++ni)
                bf[ni] = *(const short8v*)(Bs + (wn * 64 + ni * 16 + lq) * 64 +
                                           kk + g * 8);
#pragma unroll
            for (int mi = 0; mi < 4; ++mi)
#pragma unroll
                for (int ni = 0; ni < 4; ++ni)
                    acc[mi][ni] = __builtin_amdgcn_mfma_f32_16x16x32_bf16(
                        af[mi], bf[ni], acc[mi][ni], 0, 0, 0);
        }
        __syncthreads();
    }

#pragma unroll
    for (int mi = 0; mi < 4; ++mi) {
        const size_t rb = (size_t)R0 + wm * 64 + mi * 16 + g * 4;
#pragma unroll
        for (int ni = 0; ni < 4; ++ni) {
            const int col = C0 + wn * 64 + ni * 16 + lq;
            float bv = 0.f;
            if constexpr (BIAS) bv = bias[col];
#pragma unroll
            for (int r = 0; r < 4; ++r) {
                float val = acc[mi][ni][r];
                if constexpr (SCALEQ) { if (col < 256) val *= CEQ; }
                val += bv;
                if constexpr (sizeof(OUT_T) == 2)
                    Y[(rb + r) * N + col] = (OUT_T)f2bf(val);
                else
                    Y[(rb + r) * N + col] = (OUT_T)val;
            }
        }
    }
}

// ---------------------------------------------------------------------------
// Kernel 2: MFMA attention. 16 waves / block (4 waves/SIMD), one q-tile per
// wave work-unit. K: [4 g][784][8] (quarter-wave contiguous reads).
// V: packed token-pairs as u32, [32 d][404 words] (conflict-free staging
// writes AND reads). P: per-wave double buffer, software-pipelined
// score/pv order. Q pre-scaled by CEQ in GEMM1 -> exp2 direct.
// ---------------------------------------------------------------------------
#define VTP32 404                       // words per d-row (>=400, %4==0)
#define KS_SZ (LWIN * 32)               // 25088 shorts
#define VT_SH (2 * 32 * VTP32)          // 25856 shorts
#define PB_OFF (KS_SZ + VT_SH)          // 50944 shorts
#define ATTN_LDS ((PB_OFF + 16 * 1280) * 2)   // 142848 bytes

__global__ __launch_bounds__(1024, 1) void k_attn_mfma(
    const unsigned short* __restrict__ qkv,   // (25088, 768) bf16
    unsigned short* __restrict__ ao)          // (25088, 256) bf16
{
    extern __shared__ unsigned short sm[];
    unsigned short* Ks = sm;                     // [4][784][8]
    unsigned int*   Vt = (unsigned int*)(sm + KS_SZ);  // [32][404] token-pairs
    const int t = threadIdx.x;
    const int lane = t & 63, wave = t >> 6;      // wave 0..15
    const int lq = lane & 15, g = lane >> 4;
    const int h = blockIdx.x & 7, w = blockIdx.x >> 3;
    const size_t rowbase = (size_t)w * LWIN;
    const unsigned short* base = qkv + rowbase * QKVD;

    // ---- stage K ----
    for (int idx = t; idx < LWIN * 4; idx += 1024) {
        const int row = idx >> 2, c = idx & 3;
        uint4 kv = *(const uint4*)(base + (size_t)row * QKVD + 256 + h * 32 + c * 8);
        *(uint4*)(Ks + c * (LWIN * 8) + row * 8) = kv;
    }
    // ---- stage V as packed token-pairs (u32 writes: no sub-word conflicts) ----
    for (int idx = t; idx < 392 * 4; idx += 1024) {
        const int rp = idx >> 2, c = idx & 3;
        union { uint4 u; unsigned short s[8]; } a, b;
        a.u = *(const uint4*)(base + (size_t)(2 * rp) * QKVD + 512 + h * 32 + c * 8);
        b.u = *(const uint4*)(base + (size_t)(2 * rp + 1) * QKVD + 512 + h * 32 + c * 8);
#pragma unroll
        for (int j = 0; j < 8; ++j)
            Vt[(c * 8 + j) * VTP32 + rp] =
                (unsigned int)a.s[j] | ((unsigned int)b.s[j] << 16);
    }
    // zero pad words 392..403 (tokens 784..807) for the tail PV
    for (int idx = t; idx < 32 * 12; idx += 1024) {
        Vt[(idx / 12) * VTP32 + 392 + (idx % 12)] = 0;
    }
    __syncthreads();

    unsigned short* Pw = sm + PB_OFF + wave * 1280;  // 2 bufs x [16][40]

    for (int tq = wave; tq < 49; tq += 16) {
        const short8v qf = *(const short8v*)(base +
                (size_t)(tq * 16 + lq) * QKVD + h * 32 + g * 8);
        floatx4 oa0 = {0.f, 0.f, 0.f, 0.f}, oa1 = {0.f, 0.f, 0.f, 0.f};
        float lsum = 0.f;

        auto score = [&](int s, int buf) {
            short8v kf = *(const short8v*)(Ks + g * (LWIN * 8) +
                                           (size_t)(s * 16 + lq) * 8);
            floatx4 st = __builtin_amdgcn_mfma_f32_16x16x32_bf16(
                kf, qf, (floatx4){0.f, 0.f, 0.f, 0.f}, 0, 0, 0);
            float p0 = __builtin_amdgcn_exp2f(st[0]);
            float p1 = __builtin_amdgcn_exp2f(st[1]);
            float p2 = __builtin_amdgcn_exp2f(st[2]);
            float p3 = __builtin_amdgcn_exp2f(st[3]);
            lsum += (p0 + p1) + (p2 + p3);
            uint2 pw;
            pw.x = cvt_pk_bf16(p0, p1);
            pw.y = cvt_pk_bf16(p2, p3);
            *(uint2*)(Pw + buf * 640 + lq * 40 + (s & 1) * 16 + g * 4) = pw;
        };
        auto pv = [&](int u) {
            const int woff = u * 16;   // token base u*32, 2 tokens/word
            short8v v0 = *(const short8v*)(const unsigned short*)(
                Vt + (size_t)lq * VTP32 + woff + g * 4);
            short8v v1 = *(const short8v*)(const unsigned short*)(
                Vt + (size_t)(lq + 16) * VTP32 + woff + g * 4);
            short8v pf = *(const short8v*)(Pw + (u & 1) * 640 + lq * 40 + g * 8);
            oa0 = __builtin_amdgcn_mfma_f32_16x16x32_bf16(pf, v0, oa0, 0, 0, 0);
            oa1 = __builtin_amdgcn_mfma_f32_16x16x32_bf16(pf, v1, oa1, 0, 0, 0);
        };

        score(0, 0);
        score(1, 0);
        for (int u = 1; u < 24; ++u) {
            score(2 * u, u & 1);
            pv(u - 1);
            score(2 * u + 1, u & 1);
        }
        score(48, 0);    // u=24 -> buf 0, lower half
        pv(23);
        {   // zero upper half of buf 0 (tokens 784..799)
            uint2 z; z.x = 0u; z.y = 0u;
            *(uint2*)(Pw + lq * 40 + 16 + g * 4) = z;
        }
        pv(24);

        // ---- normalize + store ----
        float l = lsum;
        l += __shfl_xor(l, 16);
        l += __shfl_xor(l, 32);
        float inv = 1.f / l;
        const size_t orow0 = rowbase + (size_t)tq * 16;
#pragma unroll
        for (int r = 0; r < 4; ++r) {
            float ir = __shfl(inv, (lane & 48) | (g * 4 + r));
            size_t ob = (orow0 + g * 4 + r) * CDIM + h * 32;
            ao[ob + lq]      = f2bf(oa0[r] * ir);
            ao[ob + 16 + lq] = f2bf(oa1[r] * ir);
        }
    }
}

extern "C" void kernel_launch(void* const* d_in, const int* in_sizes, int n_in,
                              void* d_out, int out_size, void* d_ws, size_t ws_size,
                              hipStream_t stream) {
    const float* x      = (const float*)d_in[0];
    const float* qkv_w  = (const float*)d_in[1];
    const float* proj_w = (const float*)d_in[2];
    const float* proj_b = (const float*)d_in[3];
    float* out = (float*)d_out;

    unsigned short* qkvb = (unsigned short*)d_ws;
    unsigned short* xb   = qkvb + (size_t)M_ROWS * QKVD;
    unsigned short* aob  = xb;  // alias: xb dead once GEMM1 completes
    unsigned short* wqb  = xb + (size_t)M_ROWS * CDIM;
    unsigned short* wpb  = wqb + (size_t)QKVD * CDIM;

    hipFuncSetAttribute((const void*)k_attn_mfma,
                        hipFuncAttributeMaxDynamicSharedMemorySize, ATTN_LDS);

    k_f2bf<<<2048, 256, 0, stream>>>(x, xb, (M_ROWS * CDIM) / 8);
    k_f2bf<<<96, 256, 0, stream>>>(qkv_w, wqb, (QKVD * CDIM) / 8);
    k_f2bf<<<32, 256, 0, stream>>>(proj_w, wpb, (CDIM * CDIM) / 8);

    k_gemm_mfma<unsigned short, false, true>
        <<<dim3(QKVD / 128, M_ROWS / 128), 256, 0, stream>>>(
            xb, wqb, nullptr, qkvb, QKVD);

    k_attn_mfma<<<dim3(NWINH), 1024, ATTN_LDS, stream>>>(qkvb, aob);

    k_gemm_mfma<float, true, false>
        <<<dim3(CDIM / 128, M_ROWS / 128), 256, 0, stream>>>(
            aob, wpb, proj_b, out, CDIM);
}

// Round 5
// 88.120 us; speedup vs baseline: 18.5238x; 1.0253x over previous
//
#include <hip/hip_runtime.h>
#include <hip/hip_bf16.h>

// Problem constants (B=2, H=W=112, C=256, NHEAD=8, STRIP=7)
#define M_ROWS 25088
#define CDIM   256
#define QKVD   768
#define LWIN   784
#define NWINH  256   // 32 windows * 8 heads

typedef __attribute__((ext_vector_type(8))) short short8v;
typedef __attribute__((ext_vector_type(4))) float floatx4;

// scale * log2(e) = (1/sqrt(32)) * 1.4426950408889634
#define CEQ 0.2550660106245232f

static __device__ __forceinline__ unsigned short f2bf(float f) {
    unsigned int x = __float_as_uint(f);
    x += 0x7fffu + ((x >> 16) & 1u);
    return (unsigned short)(x >> 16);
}
static __device__ __forceinline__ unsigned int cvt_pk_bf16(float a, float b) {
    unsigned int r;
    asm("v_cvt_pk_bf16_f32 %0, %1, %2" : "=v"(r) : "v"(a), "v"(b));
    return r;  // lo16 = bf16(a), hi16 = bf16(b)
}
static __device__ __forceinline__ void gld_lds16(const unsigned short* g,
                                                 unsigned short* l) {
    __builtin_amdgcn_global_load_lds(
        (const __attribute__((address_space(1))) unsigned int*)g,
        (__attribute__((address_space(3))) unsigned int*)l, 16, 0, 0);
}

// ---------------------------------------------------------------------------
// Kernel 0: fp32 -> bf16 pack (8 floats / thread / iter)
// ---------------------------------------------------------------------------
__global__ __launch_bounds__(256) void k_f2bf(
    const float* __restrict__ src, unsigned short* __restrict__ dst, int n8)
{
    const float4* s4 = (const float4*)src;
    uint4* d4 = (uint4*)dst;
    for (int i = blockIdx.x * 256 + threadIdx.x; i < n8;
         i += gridDim.x * 256) {
        float4 a = s4[2 * i], b = s4[2 * i + 1];
        uint4 o;
        o.x = cvt_pk_bf16(a.x, a.y);
        o.y = cvt_pk_bf16(a.z, a.w);
        o.z = cvt_pk_bf16(b.x, b.y);
        o.w = cvt_pk_bf16(b.z, b.w);
        d4[i] = o;
    }
}

// ---------------------------------------------------------------------------
// Kernel 1/3: C(M,N) = A(M,256) @ B(N,256)^T [+ bias], bf16 MFMA.
// 128x128 tile, BK=64, 256 threads = 4 waves (2x2), 64x64 per wave.
// SCALEQ: cols 0..255 (the Q block of qkv) scaled by CEQ in the epilogue.
// ---------------------------------------------------------------------------
template <typename OUT_T, bool BIAS, bool SCALEQ>
__global__ __launch_bounds__(256, 2) void k_gemm_mfma(
    const unsigned short* __restrict__ A,   // (M, 256) bf16
    const unsigned short* __restrict__ B,   // (N, 256) bf16
    const float* __restrict__ bias,         // (N) or nullptr
    OUT_T* __restrict__ Y, int N)           // (M, N)
{
    __shared__ __attribute__((aligned(16))) unsigned short As[128 * 64];
    __shared__ __attribute__((aligned(16))) unsigned short Bs[128 * 64];
    const int t = threadIdx.x;
    const int lane = t & 63, wv = t >> 6;
    const int lq = lane & 15, g = lane >> 4;
    const int wm = wv >> 1, wn = wv & 1;
    const int R0 = blockIdx.y * 128, C0 = blockIdx.x * 128;
    const int lrow = t >> 3, lch = (t & 7) * 8;

    floatx4 acc[4][4];
#pragma unroll
    for (int i = 0; i < 4; ++i)
#pragma unroll
        for (int j = 0; j < 4; ++j) acc[i][j] = (floatx4){0.f, 0.f, 0.f, 0.f};

    for (int kc = 0; kc < 256; kc += 64) {
#pragma unroll
        for (int i = 0; i < 4; ++i) {
            gld_lds16(A + (size_t)(R0 + i * 32 + lrow) * 256 + kc + lch,
                      As + (i * 32 + wv * 8) * 64);
            gld_lds16(B + (size_t)(C0 + i * 32 + lrow) * 256 + kc + lch,
                      Bs + (i * 32 + wv * 8) * 64);
        }
        __syncthreads();
#pragma unroll
        for (int kk = 0; kk < 64; kk += 32) {
            short8v af[4], bf[4];
#pragma unroll
            for (int mi = 0; mi < 4; ++mi)
                af[mi] = *(const short8v*)(As + (wm * 64 + mi * 16 + lq) * 64 +
                                           kk + g * 8);
#pragma unroll
            for (int ni = 0; ni < 4; ++ni)
                bf[ni] = *(const short8v*)(Bs + (wn * 64 + ni * 16 + lq) * 64 +
                                           kk + g * 8);
#pragma unroll
            for (int mi = 0; mi < 4; ++mi)
#pragma unroll
                for (int ni = 0; ni < 4; ++ni)
                    acc[mi][ni] = __builtin_amdgcn_mfma_f32_16x16x32_bf16(
                        af[mi], bf[ni], acc[mi][ni], 0, 0, 0);
        }
        __syncthreads();
    }

#pragma unroll
    for (int mi = 0; mi < 4; ++mi) {
        const size_t rb = (size_t)R0 + wm * 64 + mi * 16 + g * 4;
#pragma unroll
        for (int ni = 0; ni < 4; ++ni) {
            const int col = C0 + wn * 64 + ni * 16 + lq;
            float bv = 0.f;
            if constexpr (BIAS) bv = bias[col];
#pragma unroll
            for (int r = 0; r < 4; ++r) {
                float val = acc[mi][ni][r];
                if constexpr (SCALEQ) { if (col < 256) val *= CEQ; }
                val += bv;
                if constexpr (sizeof(OUT_T) == 2)
                    Y[(rb + r) * N + col] = (OUT_T)f2bf(val);
                else
                    Y[(rb + r) * N + col] = (OUT_T)val;
            }
        }
    }
}

// ---------------------------------------------------------------------------
// Kernel 2: MFMA attention, P kept entirely in registers.
// Token k-order inside each 32-token block is permuted so the score acc's
// own cvt_pk words ARE the PV A-frag (pos 8g+j <-> token (j>=4?16:0)+4g+(j&3));
// V is staged with the matching permutation. K: [784][36] shorts
// (conflict-free reads). V: [32 d][404 u32 words] (conflict-free both ways).
// 16 waves; wave 0: 4 q-tiles, waves 1..15: 3 q-tiles.
// ---------------------------------------------------------------------------
#define KPITCH 36
#define VPITCH 404                         // u32 words per d-row
#define KS_SZ  (LWIN * KPITCH)             // 28224 shorts = 56448 B
#define ATTN_LDS (KS_SZ * 2 + 32 * VPITCH * 4)   // 108160 bytes

__global__ __launch_bounds__(1024, 1) void k_attn_mfma(
    const unsigned short* __restrict__ qkv,   // (25088, 768) bf16
    unsigned short* __restrict__ ao)          // (25088, 256) bf16
{
    extern __shared__ unsigned short sm[];
    unsigned short* Ks = sm;                           // [784][36]
    unsigned int*   Vt = (unsigned int*)(sm + KS_SZ);  // [32][404]
    const int t = threadIdx.x;
    const int lane = t & 63, wave = t >> 6;
    const int lq = lane & 15, g = lane >> 4;
    const int h = blockIdx.x & 7, w = blockIdx.x >> 3;
    const size_t rowbase = (size_t)w * LWIN;
    const unsigned short* base = qkv + rowbase * QKVD;

    // ---- stage K: [784][36], R4-style coalesced loads ----
    for (int idx = t; idx < LWIN * 4; idx += 1024) {
        const int row = idx >> 2, c = idx & 3;
        uint4 kv = *(const uint4*)(base + (size_t)row * QKVD + 256 + h * 32 + c * 8);
        *(uint4*)(Ks + row * KPITCH + c * 8) = kv;
    }
    // ---- stage V: permuted-position packed token-pairs, wave-uniform d-octet ----
    {
        const int c = t >> 8;          // d-octet 0..3 (uniform per 4-wave group)
        const int p0 = t & 255;
        for (int tp = p0; tp < 392; tp += 256) {
            const int u = tp >> 4, tpp = tp & 15;
            const int a = tpp >> 3, gg = (tpp >> 1) & 3, rp = tpp & 1;
            const int wrd = u * 16 + gg * 4 + a * 2 + rp;
            union { uint4 u4; unsigned short s[8]; } x0, x1;
            x0.u4 = *(const uint4*)(base + (size_t)(2 * tp) * QKVD + 512 + h * 32 + c * 8);
            x1.u4 = *(const uint4*)(base + (size_t)(2 * tp + 1) * QKVD + 512 + h * 32 + c * 8);
#pragma unroll
            for (int j = 0; j < 8; ++j)
                Vt[(c * 8 + j) * VPITCH + wrd] =
                    (unsigned int)x0.s[j] | ((unsigned int)x1.s[j] << 16);
        }
    }
    // zero block-24's a=1 words (positions for the missing s=49 tile)
    for (int idx = t; idx < 32 * 8; idx += 1024) {
        const int d = idx >> 3, q = idx & 7;
        Vt[d * VPITCH + 384 + (q >> 1) * 4 + 2 + (q & 1)] = 0;
    }
    __syncthreads();

    // ---- per-wave q-tiles: wave 0 -> {0..3}, wave w -> {3w+1..3w+3} ----
    const int ntile = (wave == 0) ? 4 : 3;
    const int tbase = (wave == 0) ? 0 : (3 * wave + 1);

    short8v qf[4];
#pragma unroll
    for (int n = 0; n < 4; ++n)
        if (n < ntile)
            qf[n] = *(const short8v*)(base +
                    (size_t)((tbase + n) * 16 + lq) * QKVD + h * 32 + g * 8);

    floatx4 oa[4][2];
#pragma unroll
    for (int n = 0; n < 4; ++n) {
        oa[n][0] = (floatx4){0.f, 0.f, 0.f, 0.f};
        oa[n][1] = (floatx4){0.f, 0.f, 0.f, 0.f};
    }
    float lsum[4] = {0.f, 0.f, 0.f, 0.f};

    for (int u = 0; u < 25; ++u) {
        unsigned int pw[4][4];
        {   // s = 2u
            short8v kf = *(const short8v*)(Ks + (size_t)(2 * u * 16 + lq) * KPITCH + g * 8);
#pragma unroll
            for (int n = 0; n < 4; ++n) if (n < ntile) {
                floatx4 st = __builtin_amdgcn_mfma_f32_16x16x32_bf16(
                    kf, qf[n], (floatx4){0.f, 0.f, 0.f, 0.f}, 0, 0, 0);
                float p0 = __builtin_amdgcn_exp2f(st[0]);
                float p1 = __builtin_amdgcn_exp2f(st[1]);
                float p2 = __builtin_amdgcn_exp2f(st[2]);
                float p3 = __builtin_amdgcn_exp2f(st[3]);
                lsum[n] += (p0 + p1) + (p2 + p3);
                pw[n][0] = cvt_pk_bf16(p0, p1);
                pw[n][1] = cvt_pk_bf16(p2, p3);
            }
        }
        if (u < 24) {   // s = 2u+1
            short8v kf = *(const short8v*)(Ks + (size_t)((2 * u + 1) * 16 + lq) * KPITCH + g * 8);
#pragma unroll
            for (int n = 0; n < 4; ++n) if (n < ntile) {
                floatx4 st = __builtin_amdgcn_mfma_f32_16x16x32_bf16(
                    kf, qf[n], (floatx4){0.f, 0.f, 0.f, 0.f}, 0, 0, 0);
                float p0 = __builtin_amdgcn_exp2f(st[0]);
                float p1 = __builtin_amdgcn_exp2f(st[1]);
                float p2 = __builtin_amdgcn_exp2f(st[2]);
                float p3 = __builtin_amdgcn_exp2f(st[3]);
                lsum[n] += (p0 + p1) + (p2 + p3);
                pw[n][2] = cvt_pk_bf16(p0, p1);
                pw[n][3] = cvt_pk_bf16(p2, p3);
            }
        } else {
#pragma unroll
            for (int n = 0; n < 4; ++n) if (n < ntile) {
                pw[n][2] = 0u; pw[n][3] = 0u;
            }
        }
        // ---- PV: A-frag = own pw words (permuted k-order), B = V from LDS ----
        const unsigned short* vrow0 = (const unsigned short*)Vt;
        short8v v0 = *(const short8v*)(vrow0 + (size_t)lq * (VPITCH * 2) + u * 32 + g * 8);
        short8v v1 = *(const short8v*)(vrow0 + (size_t)(lq + 16) * (VPITCH * 2) + u * 32 + g * 8);
#pragma unroll
        for (int n = 0; n < 4; ++n) if (n < ntile) {
            union { unsigned int wd[4]; short8v v; } pu;
            pu.wd[0] = pw[n][0]; pu.wd[1] = pw[n][1];
            pu.wd[2] = pw[n][2]; pu.wd[3] = pw[n][3];
            oa[n][0] = __builtin_amdgcn_mfma_f32_16x16x32_bf16(pu.v, v0, oa[n][0], 0, 0, 0);
            oa[n][1] = __builtin_amdgcn_mfma_f32_16x16x32_bf16(pu.v, v1, oa[n][1], 0, 0, 0);
        }
    }

    // ---- normalize + store ----
#pragma unroll
    for (int n = 0; n < 4; ++n) if (n < ntile) {
        float l = lsum[n];
        l += __shfl_xor(l, 16);
        l += __shfl_xor(l, 32);
        float inv = 1.f / l;
        const size_t orow0 = rowbase + (size_t)(tbase + n) * 16;
#pragma unroll
        for (int r = 0; r < 4; ++r) {
            float ir = __shfl(inv, (lane & 48) | (g * 4 + r));
            size_t ob = (orow0 + g * 4 + r) * CDIM + h * 32;
            ao[ob + lq]      = f2bf(oa[n][0][r] * ir);
            ao[ob + 16 + lq] = f2bf(oa[n][1][r] * ir);
        }
    }
}

extern "C" void kernel_launch(void* const* d_in, const int* in_sizes, int n_in,
                              void* d_out, int out_size, void* d_ws, size_t ws_size,
                              hipStream_t stream) {
    const float* x      = (const float*)d_in[0];
    const float* qkv_w  = (const float*)d_in[1];
    const float* proj_w = (const float*)d_in[2];
    const float* proj_b = (const float*)d_in[3];
    float* out = (float*)d_out;

    unsigned short* qkvb = (unsigned short*)d_ws;
    unsigned short* xb   = qkvb + (size_t)M_ROWS * QKVD;
    unsigned short* aob  = xb;  // alias: xb dead once GEMM1 completes
    unsigned short* wqb  = xb + (size_t)M_ROWS * CDIM;
    unsigned short* wpb  = wqb + (size_t)QKVD * CDIM;

    hipFuncSetAttribute((const void*)k_attn_mfma,
                        hipFuncAttributeMaxDynamicSharedMemorySize, ATTN_LDS);

    k_f2bf<<<2048, 256, 0, stream>>>(x, xb, (M_ROWS * CDIM) / 8);
    k_f2bf<<<96, 256, 0, stream>>>(qkv_w, wqb, (QKVD * CDIM) / 8);
    k_f2bf<<<32, 256, 0, stream>>>(proj_w, wpb, (CDIM * CDIM) / 8);

    k_gemm_mfma<unsigned short, false, true>
        <<<dim3(QKVD / 128, M_ROWS / 128), 256, 0, stream>>>(
            xb, wqb, nullptr, qkvb, QKVD);

    k_attn_mfma<<<dim3(NWINH), 1024, ATTN_LDS, stream>>>(qkvb, aob);

    k_gemm_mfma<float, true, false>
        <<<dim3(CDIM / 128, M_ROWS / 128), 256, 0, stream>>>(
            aob, wpb, proj_b, out, CDIM);
}